// Round 1
// baseline (1116.386 us; speedup 1.0000x reference)
//
#include <hip/hip_runtime.h>

#define K_DIM 512
#define S_DIM 64
#define T_LEN 64
#define BW    16      // sequences per workgroup
#define NWG   32      // 32 workgroups x 16 seqs = 512
#define XPAD  8       // Xb row padding (elements) to spread LDS banks

typedef float f32x4 __attribute__((ext_vector_type(4)));
typedef short bf16x8 __attribute__((ext_vector_type(8)));

__device__ __forceinline__ short f2bf(float f) {
    unsigned u = __builtin_bit_cast(unsigned, f);
    u += 0x7fffu + ((u >> 16) & 1u);   // round-to-nearest-even
    return (short)(u >> 16);
}

// ---------------- pre-pass: build bf16/derived operands in workspace ----------------
__global__ void ssm_prep(const float* __restrict__ A, const float* __restrict__ B,
                         const float* __restrict__ C, const float* __restrict__ Pp,
                         short* __restrict__ A16, short* __restrict__ Ceff16,
                         float* __restrict__ PI32, float* __restrict__ PB32) {
    int i = blockIdx.x * blockDim.x + threadIdx.x;
    int stride = gridDim.x * blockDim.x;
    for (int idx = i; idx < K_DIM * K_DIM; idx += stride)
        A16[idx] = f2bf(A[idx]);
    for (int idx = i; idx < S_DIM * K_DIM; idx += stride) {
        int s = idx >> 9;               // K_DIM == 512
        int k = idx & (K_DIM - 1);
        float p = 1.0f / (1.0f + expf(-Pp[idx]));
        PI32[idx]   = p;
        Ceff16[idx] = f2bf(C[idx] * p);
        PB32[idx]   = p * B[k * S_DIM + s];   // pi[s][k] * B[k][s]
    }
}

// ---------------- main: 32 WGs x 512 threads, 16 seqs/WG, 64 sequential steps ----------------
__global__ __launch_bounds__(512, 2) void ssm_main(
    const short* __restrict__ A16,     // [K][K] bf16 row-major
    const short* __restrict__ Ceff16,  // [S][K] bf16
    const float* __restrict__ PI32,    // [S][K]
    const float* __restrict__ PB32,    // [S][K]
    const float* __restrict__ init,    // [K]
    const int*   __restrict__ tokens,  // [BSZ][T]
    float*       __restrict__ out)     // [BSZ]
{
    __shared__ short Xb[BW][K_DIM + XPAD];   // bf16 state copy (MFMA A-operand)
    __shared__ float Lg[2][BW][S_DIM + 1];   // logits partials (two K-halves)
    __shared__ int   tokS[BW][T_LEN];

    const int tid = threadIdx.x;
    const int w  = tid >> 6;     // wave 0..7, owns k-range [w*64, w*64+64)
    const int l  = tid & 63;
    const int lg = l >> 4;       // lane group 0..3
    const int lr = l & 15;       // row/col index within tile
    const int b0 = blockIdx.x * BW;

    // stage tokens for this WG's 16 sequences
    for (int idx = tid; idx < BW * T_LEN; idx += 512) {
        int r = idx >> 6, t = idx & 63;
        tokS[r][t] = tokens[(b0 + r) * T_LEN + t];
    }
    // init bf16 state: x[b][k] = init[k]
    for (int idx = tid; idx < BW * K_DIM; idx += 512) {
        int r = idx >> 9, k = idx & (K_DIM - 1);
        Xb[r][k] = f2bf(init[k]);
    }
    // fp32 master state in registers: xm[nt][e] = x[b=4*lg+e][k=w*64+nt*16+lr]
    float xm[4][4];
    #pragma unroll
    for (int nt = 0; nt < 4; ++nt) {
        float iv = init[w * 64 + nt * 16 + lr];
        #pragma unroll
        for (int e = 0; e < 4; ++e) xm[nt][e] = iv;
    }
    float llacc = 0.0f;
    __syncthreads();

    const int h  = w >> 2;   // logits K-half (0: j<256, 1: j>=256)
    const int sq = w & 3;    // logits s-tile

    for (int t = 0; t < T_LEN; ++t) {
        // ---- P1: logits partial GEMM: Lg[h][b][s] = sum_{j in half} x[b][j]*Ceff[s][j]
        f32x4 lgacc = {0.f, 0.f, 0.f, 0.f};
        #pragma unroll 4
        for (int ji = 0; ji < 8; ++ji) {
            int jb = h * 256 + ji * 32;
            bf16x8 xa = *(const bf16x8*)(&Xb[lr][jb + 8 * lg]);
            bf16x8 cb = *(const bf16x8*)(Ceff16 + (sq * 16 + lr) * K_DIM + jb + 8 * lg);
            lgacc = __builtin_amdgcn_mfma_f32_16x16x32_bf16(xa, cb, lgacc, 0, 0, 0);
        }
        #pragma unroll
        for (int e = 0; e < 4; ++e)
            Lg[h][4 * lg + e][sq * 16 + lr] = lgacc[e];

        // ---- gating prefetch (per-element pi / pi*Bt rows for this step's tokens)
        int mytok[4];
        #pragma unroll
        for (int e = 0; e < 4; ++e) mytok[e] = tokS[4 * lg + e][t];
        float pi_v[4][4], pb_v[4][4];
        #pragma unroll
        for (int nt = 0; nt < 4; ++nt) {
            int k = w * 64 + nt * 16 + lr;
            #pragma unroll
            for (int e = 0; e < 4; ++e) {
                pi_v[nt][e] = PI32[mytok[e] * K_DIM + k];
                pb_v[nt][e] = PB32[mytok[e] * K_DIM + k];
            }
        }

        // ---- P2: update GEMM: acc[nt] = sum_j x[b][j] * A[k][j], k = w*64+nt*16+lr
        f32x4 acc[4];
        #pragma unroll
        for (int nt = 0; nt < 4; ++nt) acc[nt] = (f32x4){0.f, 0.f, 0.f, 0.f};
        #pragma unroll 4
        for (int ji = 0; ji < 16; ++ji) {
            int jb = ji * 32;
            bf16x8 xa = *(const bf16x8*)(&Xb[lr][jb + 8 * lg]);
            #pragma unroll
            for (int nt = 0; nt < 4; ++nt) {
                bf16x8 ab = *(const bf16x8*)(A16 + (w * 64 + nt * 16 + lr) * K_DIM + jb + 8 * lg);
                acc[nt] = __builtin_amdgcn_mfma_f32_16x16x32_bf16(xa, ab, acc[nt], 0, 0, 0);
            }
        }
        __syncthreads();   // everyone done reading Xb + Lg writes visible

        // ---- P3: gating in fp32 regs, rewrite Xb
        #pragma unroll
        for (int nt = 0; nt < 4; ++nt) {
            int k = w * 64 + nt * 16 + lr;
            #pragma unroll
            for (int e = 0; e < 4; ++e) {
                float p  = pi_v[nt][e];
                float nx = xm[nt][e] + p * (acc[nt][e] - xm[nt][e]) + pb_v[nt][e];
                xm[nt][e] = nx;
                Xb[4 * lg + e][k] = f2bf(nx);
            }
        }
        // wave 0: log-softmax + token gather + LL accumulation (16 rows x 64 logits)
        if (w == 0) {
            int b = l >> 2, q = l & 3;
            float v[16];
            #pragma unroll
            for (int i2 = 0; i2 < 16; ++i2)
                v[i2] = Lg[0][b][q * 16 + i2] + Lg[1][b][q * 16 + i2];
            float m = v[0];
            #pragma unroll
            for (int i2 = 1; i2 < 16; ++i2) m = fmaxf(m, v[i2]);
            m = fmaxf(m, __shfl_xor(m, 1));
            m = fmaxf(m, __shfl_xor(m, 2));
            float sum = 0.f;
            #pragma unroll
            for (int i2 = 0; i2 < 16; ++i2) sum += expf(v[i2] - m);
            sum += __shfl_xor(sum, 1);
            sum += __shfl_xor(sum, 2);
            int tok = tokS[b][t];
            float sel = (q == (tok >> 4)) ? v[tok & 15] : 0.0f;
            sel += __shfl_xor(sel, 1);
            sel += __shfl_xor(sel, 2);
            llacc += sel - m - logf(sum);
        }
        __syncthreads();   // new Xb visible; Lg consumed
    }

    if (w == 0 && (l & 3) == 0)
        out[b0 + (l >> 2)] = llacc;
}

extern "C" void kernel_launch(void* const* d_in, const int* in_sizes, int n_in,
                              void* d_out, int out_size, void* d_ws, size_t ws_size,
                              hipStream_t stream) {
    const float* A  = (const float*)d_in[0];   // (512,512)
    const float* B  = (const float*)d_in[1];   // (512,64)
    const float* C  = (const float*)d_in[2];   // (64,512)
    const float* Pp = (const float*)d_in[3];   // (64,512)
    const float* init = (const float*)d_in[4]; // (512,)
    const int* tokens = (const int*)d_in[5];   // (512,64)
    float* out = (float*)d_out;

    // workspace layout (needs 851,968 bytes)
    short* A16    = (short*)d_ws;                              // 512*512*2 = 524288
    short* Ceff16 = (short*)((char*)d_ws + 524288);            // 64*512*2  =  65536
    float* PI32   = (float*)((char*)d_ws + 589824);            // 64*512*4  = 131072
    float* PB32   = (float*)((char*)d_ws + 720896);            // 64*512*4  = 131072

    ssm_prep<<<256, 256, 0, stream>>>(A, B, C, Pp, A16, Ceff16, PI32, PB32);
    ssm_main<<<NWG, 512, 0, stream>>>(A16, Ceff16, PI32, PB32, init, tokens, out);
}

// Round 3
// 738.131 us; speedup vs baseline: 1.5124x; 1.5124x over previous
//
#include <hip/hip_runtime.h>

#define K_DIM 512
#define S_DIM 64
#define T_LEN 64
#define BW    16      // sequences per workgroup
#define NWG   32      // 32 workgroups x 16 seqs = 512
#define XPAD  8       // Xb row padding (elements): row stride 1040B -> conflict-free b128
#define PFD   4       // A-fragment prefetch depth. MUST divide 16 (phase alignment of
                      // the rolling slots across steps; PFD=6 was the R2 correctness bug)

typedef float f32x4 __attribute__((ext_vector_type(4)));
typedef short bf16x8 __attribute__((ext_vector_type(8)));

__device__ __forceinline__ short f2bf(float f) {
    unsigned u = __builtin_bit_cast(unsigned, f);
    u += 0x7fffu + ((u >> 16) & 1u);   // round-to-nearest-even
    return (short)(u >> 16);
}

// ---------------- pre-pass: build bf16/derived operands in workspace ----------------
__global__ void ssm_prep(const float* __restrict__ A, const float* __restrict__ B,
                         const float* __restrict__ C, const float* __restrict__ Pp,
                         short* __restrict__ A16, short* __restrict__ Ceff16,
                         float* __restrict__ PI32, float* __restrict__ PB32) {
    int i = blockIdx.x * blockDim.x + threadIdx.x;
    int stride = gridDim.x * blockDim.x;
    for (int idx = i; idx < K_DIM * K_DIM; idx += stride)
        A16[idx] = f2bf(A[idx]);
    for (int idx = i; idx < S_DIM * K_DIM; idx += stride) {
        int s = idx >> 9;               // K_DIM == 512
        int k = idx & (K_DIM - 1);
        float p = 1.0f / (1.0f + expf(-Pp[idx]));
        PI32[idx]   = p;
        Ceff16[idx] = f2bf(C[idx] * p);
        PB32[idx]   = p * B[k * S_DIM + s];   // pi[s][k] * B[k][s]
    }
}

// ---------------- main: 32 WGs x 1024 threads (16 waves), 16 seqs/WG, 64 steps ----------------
__global__ __launch_bounds__(1024, 4) void ssm_main(
    const short* __restrict__ A16,     // [K][K] bf16 row-major
    const short* __restrict__ Ceff16,  // [S][K] bf16
    const float* __restrict__ PI32,    // [S][K]
    const float* __restrict__ PB32,    // [S][K]
    const float* __restrict__ init,    // [K]
    const int*   __restrict__ tokens,  // [BSZ][T]
    float*       __restrict__ out)     // [BSZ]
{
    __shared__ short Xb[BW][K_DIM + XPAD];      // bf16 state (MFMA A-operand), 16.6 KB
    __shared__ float Lg[4][BW][S_DIM + 4];      // logits partials (4 K-quarters), 17.4 KB
    __shared__ int   tokS[BW][T_LEN];           // 4 KB

    const int tid = threadIdx.x;
    const int w  = tid >> 6;     // wave 0..15, owns k-range [w*32, w*32+32)
    const int l  = tid & 63;
    const int lg = l >> 4;       // lane group 0..3
    const int lr = l & 15;       // row/col index within MFMA tile
    const int b0 = blockIdx.x * BW;

    // stage tokens for this WG's 16 sequences
    for (int idx = tid; idx < BW * T_LEN; idx += 1024) {
        int r = idx >> 6, t = idx & 63;
        tokS[r][t] = tokens[(b0 + r) * T_LEN + t];
    }
    // init bf16 state: x[b][k] = init[k]
    for (int idx = tid; idx < BW * K_DIM; idx += 1024) {
        int r = idx >> 9, k = idx & (K_DIM - 1);
        Xb[r][k] = f2bf(init[k]);
    }
    // fp32 master state: xm[nt][e] = x[b=4*lg+e][k=w*32+nt*16+lr]
    float xm[2][4];
    #pragma unroll
    for (int nt = 0; nt < 2; ++nt) {
        float iv = init[w * 32 + nt * 16 + lr];
        #pragma unroll
        for (int e = 0; e < 4; ++e) xm[nt][e] = iv;
    }

    // hoisted Ceff fragments (step-invariant): wave covers s-tile sq, K-quarter qh
    const int sq = w & 3;
    const int qh = w >> 2;
    bf16x8 cfr[4];
    #pragma unroll
    for (int i = 0; i < 4; ++i)
        cfr[i] = *(const bf16x8*)(Ceff16 + (sq * 16 + lr) * K_DIM + qh * 128 + i * 32 + 8 * lg);

    // A-fragment rolling prefetch pipeline (addresses step-invariant)
    const short* aP0 = A16 + (w * 32 +      lr) * K_DIM + 8 * lg;
    const short* aP1 = A16 + (w * 32 + 16 + lr) * K_DIM + 8 * lg;
    bf16x8 af0[PFD], af1[PFD];
    #pragma unroll
    for (int d = 0; d < PFD; ++d) {
        af0[d] = *(const bf16x8*)(aP0 + d * 32);
        af1[d] = *(const bf16x8*)(aP1 + d * 32);
    }

    float llacc = 0.0f;
    __syncthreads();

    for (int t = 0; t < T_LEN; ++t) {
        // ---- issue gating gathers early (consumed in P3, far below)
        int mytok[4];
        #pragma unroll
        for (int e = 0; e < 4; ++e) mytok[e] = tokS[4 * lg + e][t];
        float pi_v[2][4], pb_v[2][4];
        #pragma unroll
        for (int nt = 0; nt < 2; ++nt) {
            int k = w * 32 + nt * 16 + lr;
            #pragma unroll
            for (int e = 0; e < 4; ++e) {
                pi_v[nt][e] = PI32[mytok[e] * K_DIM + k];
                pb_v[nt][e] = PB32[mytok[e] * K_DIM + k];
            }
        }

        // ---- P1: logits partial GEMM (K-quarter qh): 4 MFMA, operands hoisted/LDS
        f32x4 lga = {0.f, 0.f, 0.f, 0.f};
        #pragma unroll
        for (int i = 0; i < 4; ++i) {
            bf16x8 xa = *(const bf16x8*)(&Xb[lr][qh * 128 + i * 32 + 8 * lg]);
            lga = __builtin_amdgcn_mfma_f32_16x16x32_bf16(xa, cfr[i], lga, 0, 0, 0);
        }
        #pragma unroll
        for (int e = 0; e < 4; ++e)
            Lg[qh][4 * lg + e][sq * 16 + lr] = lga[e];

        // ---- P2: update GEMM with rolling A-prefetch:
        //      consume af[ji%PFD] (== frag ji), then reload slot with frag (ji+PFD)&15.
        //      Iters 12..15 prefetch frags 0..3 for the NEXT step across the barrier;
        //      since PFD | 16, slot s holds frag s at every step boundary.
        f32x4 acc0 = {0.f, 0.f, 0.f, 0.f};
        f32x4 acc1 = {0.f, 0.f, 0.f, 0.f};
        #pragma unroll
        for (int ji = 0; ji < 16; ++ji) {
            bf16x8 xa = *(const bf16x8*)(&Xb[lr][ji * 32 + 8 * lg]);
            acc0 = __builtin_amdgcn_mfma_f32_16x16x32_bf16(xa, af0[ji % PFD], acc0, 0, 0, 0);
            acc1 = __builtin_amdgcn_mfma_f32_16x16x32_bf16(xa, af1[ji % PFD], acc1, 0, 0, 0);
            const int jn = (ji + PFD) & 15;
            af0[ji % PFD] = *(const bf16x8*)(aP0 + jn * 32);
            af1[ji % PFD] = *(const bf16x8*)(aP1 + jn * 32);
        }
        __syncthreads();   // Xb reads done; Lg writes visible

        // ---- P3: gating in fp32, rewrite Xb
        #pragma unroll
        for (int nt = 0; nt < 2; ++nt) {
            int k = w * 32 + nt * 16 + lr;
            #pragma unroll
            for (int e = 0; e < 4; ++e) {
                float a  = (nt == 0) ? acc0[e] : acc1[e];
                float p  = pi_v[nt][e];
                float nx = xm[nt][e] + p * (a - xm[nt][e]) + pb_v[nt][e];
                xm[nt][e] = nx;
                Xb[4 * lg + e][k] = f2bf(nx);
            }
        }
        // wave 0: log-softmax + token gather + LL accumulation (16 rows x 64 logits)
        if (w == 0) {
            int b = l >> 2, q = l & 3;
            float v[16];
            #pragma unroll
            for (int i2 = 0; i2 < 16; ++i2)
                v[i2] = Lg[0][b][q * 16 + i2] + Lg[1][b][q * 16 + i2]
                      + Lg[2][b][q * 16 + i2] + Lg[3][b][q * 16 + i2];
            float m = v[0];
            #pragma unroll
            for (int i2 = 1; i2 < 16; ++i2) m = fmaxf(m, v[i2]);
            m = fmaxf(m, __shfl_xor(m, 1));
            m = fmaxf(m, __shfl_xor(m, 2));
            float sum = 0.f;
            #pragma unroll
            for (int i2 = 0; i2 < 16; ++i2) sum += expf(v[i2] - m);
            sum += __shfl_xor(sum, 1);
            sum += __shfl_xor(sum, 2);
            int tok = tokS[b][t];
            float sel = (q == (tok >> 4)) ? v[tok & 15] : 0.0f;
            sel += __shfl_xor(sel, 1);
            sel += __shfl_xor(sel, 2);
            llacc += sel - m - logf(sum);
        }
        __syncthreads();   // new Xb visible; Lg consumed
    }

    if (w == 0 && (l & 3) == 0)
        out[b0 + (l >> 2)] = llacc;
}

extern "C" void kernel_launch(void* const* d_in, const int* in_sizes, int n_in,
                              void* d_out, int out_size, void* d_ws, size_t ws_size,
                              hipStream_t stream) {
    const float* A  = (const float*)d_in[0];   // (512,512)
    const float* B  = (const float*)d_in[1];   // (512,64)
    const float* C  = (const float*)d_in[2];   // (64,512)
    const float* Pp = (const float*)d_in[3];   // (64,512)
    const float* init = (const float*)d_in[4]; // (512,)
    const int* tokens = (const int*)d_in[5];   // (512,64)
    float* out = (float*)d_out;

    // workspace layout (needs 851,968 bytes)
    short* A16    = (short*)d_ws;                              // 512*512*2 = 524288
    short* Ceff16 = (short*)((char*)d_ws + 524288);            // 64*512*2  =  65536
    float* PI32   = (float*)((char*)d_ws + 589824);            // 64*512*4  = 131072
    float* PB32   = (float*)((char*)d_ws + 720896);            // 64*512*4  = 131072

    ssm_prep<<<256, 256, 0, stream>>>(A, B, C, Pp, A16, Ceff16, PI32, PB32);
    ssm_main<<<NWG, 1024, 0, stream>>>(A16, Ceff16, PI32, PB32, init, tokens, out);
}

// Round 4
// 659.432 us; speedup vs baseline: 1.6930x; 1.1193x over previous
//
#include <hip/hip_runtime.h>

#define K_DIM 512
#define S_DIM 64
#define T_LEN 64
#define BW    16      // sequences per workgroup
#define NWG   32      // 32 workgroups x 16 seqs = 512
#define XPAD  8       // Xb row padding (elements)

typedef float f32x4 __attribute__((ext_vector_type(4)));
typedef short bf16x8 __attribute__((ext_vector_type(8)));

__device__ __forceinline__ short f2bf(float f) {
    unsigned u = __builtin_bit_cast(unsigned, f);
    u += 0x7fffu + ((u >> 16) & 1u);   // round-to-nearest-even
    return (short)(u >> 16);
}

// ---------------- pre-pass: build bf16/derived operands in workspace ----------------
__global__ void ssm_prep(const float* __restrict__ A, const float* __restrict__ B,
                         const float* __restrict__ C, const float* __restrict__ Pp,
                         short* __restrict__ A16, short* __restrict__ Ceff16,
                         float* __restrict__ PI32, float* __restrict__ PB32) {
    int i = blockIdx.x * blockDim.x + threadIdx.x;
    int stride = gridDim.x * blockDim.x;
    for (int idx = i; idx < K_DIM * K_DIM; idx += stride)
        A16[idx] = f2bf(A[idx]);
    for (int idx = i; idx < S_DIM * K_DIM; idx += stride) {
        int s = idx >> 9;               // K_DIM == 512
        int k = idx & (K_DIM - 1);
        float p = 1.0f / (1.0f + expf(-Pp[idx]));
        PI32[idx]   = p;
        Ceff16[idx] = f2bf(C[idx] * p);
        PB32[idx]   = p * B[k * S_DIM + s];   // pi[s][k] * B[k][s]
    }
}

// ---------------- main: 32 WGs x 1024 threads (16 waves), 16 seqs/WG, 64 steps ----------------
// waves_per_eu(4,4): pin exactly 4 waves/SIMD -> 128-VGPR budget. R3's compiler
// squeezed to 64 VGPRs (8 waves/EU target) and spilled the pipeline to scratch
// (WRITE_SIZE 2KB -> 10.7MB).
__global__ __launch_bounds__(1024) __attribute__((amdgpu_waves_per_eu(4, 4)))
void ssm_main(
    const short* __restrict__ A16,     // [K][K] bf16 row-major
    const short* __restrict__ Ceff16,  // [S][K] bf16
    const float* __restrict__ PI32,    // [S][K]
    const float* __restrict__ PB32,    // [S][K]
    const float* __restrict__ init,    // [K]
    const int*   __restrict__ tokens,  // [BSZ][T]
    float*       __restrict__ out)     // [BSZ]
{
    __shared__ short Xb[BW][K_DIM + XPAD];      // bf16 state (MFMA A-operand)
    __shared__ float Lg[4][BW][S_DIM + 5];      // logits partials (4 K-quarters)
    __shared__ int   tokS[BW][T_LEN];

    const int tid = threadIdx.x;
    const int w  = tid >> 6;     // wave 0..15, owns k-range [w*32, w*32+32)
    const int l  = tid & 63;
    const int lg = l >> 4;       // lane group 0..3
    const int lr = l & 15;       // row/col index within MFMA tile
    const int b0 = blockIdx.x * BW;

    // stage tokens for this WG's 16 sequences
    for (int idx = tid; idx < BW * T_LEN; idx += 1024) {
        int r = idx >> 6, t = idx & 63;
        tokS[r][t] = tokens[(b0 + r) * T_LEN + t];
    }
    // init bf16 state: x[b][k] = init[k]
    for (int idx = tid; idx < BW * K_DIM; idx += 1024) {
        int r = idx >> 9, k = idx & (K_DIM - 1);
        Xb[r][k] = f2bf(init[k]);
    }
    // fp32 master state: xm[nt][e] = x[b=4*lg+e][k=w*32+nt*16+lr]
    float xm[2][4];
    #pragma unroll
    for (int nt = 0; nt < 2; ++nt) {
        float iv = init[w * 32 + nt * 16 + lr];
        #pragma unroll
        for (int e = 0; e < 4; ++e) xm[nt][e] = iv;
    }

    const int sq = w & 3;    // logits s-tile
    const int qh = w >> 2;   // logits K-quarter

    // A-fragment bases: nt=0 rows (k = w*32+lr), nt=1 rows (k = w*32+16+lr)
    const short* aP0 = A16 + (w * 32 +      lr) * K_DIM + 8 * lg;
    const short* aP1 = A16 + (w * 32 + 16 + lr) * K_DIM + 8 * lg;

    // nt=0 A-tile PERMANENTLY register-resident: 16 frags x 16B = 64 VGPR,
    // loaded once, reused for all 64 steps (A is step-invariant).
    bf16x8 ah[16];
    #pragma unroll
    for (int jb = 0; jb < 16; ++jb)
        ah[jb] = *(const bf16x8*)(aP0 + jb * 32);

    // nt=1 A-tile: rolling 4-deep prefetch (4 divides 16 -> phase-aligned)
    bf16x8 af1[4];
    #pragma unroll
    for (int d = 0; d < 4; ++d)
        af1[d] = *(const bf16x8*)(aP1 + d * 32);

    float llacc = 0.0f;
    __syncthreads();

    for (int t = 0; t < T_LEN; ++t) {
        // ---- P1: logits partial GEMM (K-quarter qh): 4 MFMA; cfr re-read from
        //      L2 each step (addresses invariant -> L2-hot) to save registers
        f32x4 lga = {0.f, 0.f, 0.f, 0.f};
        #pragma unroll
        for (int i = 0; i < 4; ++i) {
            bf16x8 cb = *(const bf16x8*)(Ceff16 + (sq * 16 + lr) * K_DIM + qh * 128 + i * 32 + 8 * lg);
            bf16x8 xa = *(const bf16x8*)(&Xb[lr][qh * 128 + i * 32 + 8 * lg]);
            lga = __builtin_amdgcn_mfma_f32_16x16x32_bf16(xa, cb, lga, 0, 0, 0);
        }
        #pragma unroll
        for (int e = 0; e < 4; ++e)
            Lg[qh][4 * lg + e][sq * 16 + lr] = lga[e];

        // ---- P2: update GEMM. nt=0 from registers (zero loads), nt=1 rolling.
        f32x4 acc0 = {0.f, 0.f, 0.f, 0.f};
        f32x4 acc1 = {0.f, 0.f, 0.f, 0.f};
        #pragma unroll
        for (int ji = 0; ji < 16; ++ji) {
            bf16x8 xa = *(const bf16x8*)(&Xb[lr][ji * 32 + 8 * lg]);
            acc0 = __builtin_amdgcn_mfma_f32_16x16x32_bf16(xa, ah[ji],      acc0, 0, 0, 0);
            acc1 = __builtin_amdgcn_mfma_f32_16x16x32_bf16(xa, af1[ji & 3], acc1, 0, 0, 0);
            af1[ji & 3] = *(const bf16x8*)(aP1 + ((ji + 4) & 15) * 32);
        }
        __syncthreads();   // Xb reads done; Lg writes visible

        // ---- P3: gating in fp32, rewrite Xb (pi/pb gathers are P3-local;
        //      latency overlapped by the other 3 waves on this SIMD)
        int mytok[4];
        #pragma unroll
        for (int e = 0; e < 4; ++e) mytok[e] = tokS[4 * lg + e][t];
        #pragma unroll
        for (int nt = 0; nt < 2; ++nt) {
            int k = w * 32 + nt * 16 + lr;
            #pragma unroll
            for (int e = 0; e < 4; ++e) {
                float p  = PI32[mytok[e] * K_DIM + k];
                float pb = PB32[mytok[e] * K_DIM + k];
                float a  = (nt == 0) ? acc0[e] : acc1[e];
                float nx = xm[nt][e] + p * (a - xm[nt][e]) + pb;
                xm[nt][e] = nx;
                Xb[4 * lg + e][k] = f2bf(nx);
            }
        }
        // waves 0..3: log-softmax + LL for 4 seqs each (16 lanes/seq, 4 logits/lane)
        if (w < 4) {
            int b = w * 4 + (l >> 4);
            int i = l & 15;
            float v[4];
            #pragma unroll
            for (int c = 0; c < 4; ++c)
                v[c] = Lg[0][b][i * 4 + c] + Lg[1][b][i * 4 + c]
                     + Lg[2][b][i * 4 + c] + Lg[3][b][i * 4 + c];
            float m = fmaxf(fmaxf(v[0], v[1]), fmaxf(v[2], v[3]));
            m = fmaxf(m, __shfl_xor(m, 1));
            m = fmaxf(m, __shfl_xor(m, 2));
            m = fmaxf(m, __shfl_xor(m, 4));
            m = fmaxf(m, __shfl_xor(m, 8));
            float sum = expf(v[0] - m) + expf(v[1] - m) + expf(v[2] - m) + expf(v[3] - m);
            sum += __shfl_xor(sum, 1);
            sum += __shfl_xor(sum, 2);
            sum += __shfl_xor(sum, 4);
            sum += __shfl_xor(sum, 8);
            int tok = tokS[b][t];
            float sel = (i == (tok >> 2)) ? v[tok & 3] : 0.0f;
            sel += __shfl_xor(sel, 1);
            sel += __shfl_xor(sel, 2);
            sel += __shfl_xor(sel, 4);
            sel += __shfl_xor(sel, 8);
            llacc += sel - m - logf(sum);
        }
        __syncthreads();   // new Xb visible; Lg consumed
    }

    if (w < 4 && (l & 15) == 0)
        out[b0 + w * 4 + (l >> 4)] = llacc;
}

extern "C" void kernel_launch(void* const* d_in, const int* in_sizes, int n_in,
                              void* d_out, int out_size, void* d_ws, size_t ws_size,
                              hipStream_t stream) {
    const float* A  = (const float*)d_in[0];   // (512,512)
    const float* B  = (const float*)d_in[1];   // (512,64)
    const float* C  = (const float*)d_in[2];   // (64,512)
    const float* Pp = (const float*)d_in[3];   // (64,512)
    const float* init = (const float*)d_in[4]; // (512,)
    const int* tokens = (const int*)d_in[5];   // (512,64)
    float* out = (float*)d_out;

    // workspace layout (needs 851,968 bytes)
    short* A16    = (short*)d_ws;                              // 512*512*2 = 524288
    short* Ceff16 = (short*)((char*)d_ws + 524288);            // 64*512*2  =  65536
    float* PI32   = (float*)((char*)d_ws + 589824);            // 64*512*4  = 131072
    float* PB32   = (float*)((char*)d_ws + 720896);            // 64*512*4  = 131072

    ssm_prep<<<256, 256, 0, stream>>>(A, B, C, Pp, A16, Ceff16, PI32, PB32);
    ssm_main<<<NWG, 1024, 0, stream>>>(A16, Ceff16, PI32, PB32, init, tokens, out);
}